// Round 8
// baseline (116.576 us; speedup 1.0000x reference)
//
#include <hip/hip_runtime.h>
#include <hip/hip_bf16.h>

#define EPSV 1e-5f
static const int B_ = 16, S_ = 200, D_ = 512, H_ = 8, FF_ = 2048, P_ = 10, HD_ = 64;
static const int SP = 224;  // padded sequence length (14 x 16)

typedef __bf16 bf16_t;
typedef __attribute__((ext_vector_type(8))) __bf16 bf16x8;
typedef __attribute__((ext_vector_type(4))) __bf16 bf16x4;
typedef __attribute__((ext_vector_type(4))) float f32x4;

__device__ __forceinline__ void gload16(const void* g, void* l) {
    __builtin_amdgcn_global_load_lds(
        (const __attribute__((address_space(1))) void*)g,
        (__attribute__((address_space(3))) void*)l, 16, 0, 0);
}

// ---------------------------------------------------------------------------
// bf16 MFMA GEMM: C[M,N] = A[M,K] @ B[N,K]^T, 256 thr / 4 waves.
// BM=128, BN=64 -> wave computes 64x32 (16 MFMA per K-step).
// Double-buffered LDS + COUNTED vmcnt(6): prefetch loads stay in flight
// across the barrier (T3/T4). Raw s_barrier, never __syncthreads.
// XOR source-swizzle (T2): LDS phys chunk p of row r holds global chunk
// p ^ (r&7); readers apply the same XOR -> 16-way bank conflict killed.
// EPI: 1 = +bias,relu -> bf16 ; 3 = +bias, scatter K/Vt bf16 (strides SP) ;
//      5 = split-K partial -> f32 (no bias)
// ---------------------------------------------------------------------------
template <int BM, int BN, int WROWS, int WCOLS, int EPI>
__global__ __launch_bounds__(256) void mfma_gemm(
    const bf16_t* __restrict__ A,
    const bf16_t* __restrict__ Bw,
    float* __restrict__ Cf, bf16_t* __restrict__ Cb, long cBat, int ldc,
    const float* __restrict__ bias,
    bf16_t* __restrict__ kOut, bf16_t* __restrict__ vtOut,
    int M, int N, int K, int kcPerSplit)
{
    constexpr int MR = WROWS / 16, NR = WCOLS / 16;
    constexpr int NWC = BN / WCOLS;
    constexpr int NLOADS = BM / 32 + BN / 32;  // gload16s per thread per stage
    static_assert((4 / NWC) * WROWS == BM, "wave tiling must cover BM");
    static_assert(NWC * WCOLS == BN, "wave tiling must cover BN");
    static_assert(NLOADS == 6, "vmcnt literal below assumes 6 loads/stage");

    __shared__ bf16_t Asm[2][BM * 64];
    __shared__ bf16_t Bsm[2][BN * 64];

    const int wv = threadIdx.x >> 6;
    const int ln = threadIdx.x & 63;
    const int split = blockIdx.z;
    const int rowBase = blockIdx.y * BM;
    const int colBase = blockIdx.x * BN;
    const int wr = (wv / NWC) * WROWS;
    const int wc = (wv % NWC) * WCOLS;

    const int lr8 = ln >> 3;                    // row within 8-row group
    const int csw = ((ln & 7) ^ lr8) * 8;       // swizzled source chunk offset

    f32x4 acc[MR][NR] = {};

    const int kBeg = split * kcPerSplit;
    const int kEnd = kBeg + kcPerSplit;

    auto STAGE = [&](int k0, int buf) {
        #pragma unroll
        for (int i = 0; i < BM / 32; i++) {
            int row = i * 32 + wv * 8 + lr8;
            int gr = rowBase + row; gr = (gr < M) ? gr : (M - 1);
            gload16(A + (long)gr * K + k0 + csw, &Asm[buf][(i * 32 + wv * 8) * 64]);
        }
        #pragma unroll
        for (int i = 0; i < BN / 32; i++) {
            int col = i * 32 + wv * 8 + lr8;
            int gc = colBase + col; gc = (gc < N) ? gc : (N - 1);
            gload16(Bw + (long)gc * K + k0 + csw, &Bsm[buf][(i * 32 + wv * 8) * 64]);
        }
    };

    auto COMPUTE = [&](int buf) {
        #pragma unroll
        for (int kk = 0; kk < 2; kk++) {
            bf16x8 af[MR], bfr[NR];
            #pragma unroll
            for (int m = 0; m < MR; m++) {
                int r = wr + m * 16 + (ln & 15);
                int pc = (kk * 4 + (ln >> 4)) ^ (r & 7);
                af[m] = *reinterpret_cast<const bf16x8*>(&Asm[buf][r * 64 + pc * 8]);
            }
            #pragma unroll
            for (int n = 0; n < NR; n++) {
                int r = wc + n * 16 + (ln & 15);
                int pc = (kk * 4 + (ln >> 4)) ^ (r & 7);
                bfr[n] = *reinterpret_cast<const bf16x8*>(&Bsm[buf][r * 64 + pc * 8]);
            }
            #pragma unroll
            for (int m = 0; m < MR; m++)
                #pragma unroll
                for (int n = 0; n < NR; n++)
                    acc[m][n] = __builtin_amdgcn_mfma_f32_16x16x32_bf16(
                        af[m], bfr[n], acc[m][n], 0, 0, 0);
        }
    };

    // prologue
    STAGE(kBeg, 0);

    int t = 0;
    for (int k0 = kBeg; k0 < kEnd; k0 += 64, ++t) {
        const bool has_next = (k0 + 64 < kEnd);
        if (has_next) {
            STAGE(k0 + 64, (t + 1) & 1);
            asm volatile("s_waitcnt vmcnt(6)" ::: "memory");  // cur landed, next in flight
        } else {
            asm volatile("s_waitcnt vmcnt(0)" ::: "memory");
        }
        __builtin_amdgcn_s_barrier();
        __builtin_amdgcn_sched_barrier(0);
        COMPUTE(t & 1);
        if (has_next) {
            __builtin_amdgcn_sched_barrier(0);
            __builtin_amdgcn_s_barrier();  // all waves done reading before overwrite
        }
    }

    #pragma unroll
    for (int m = 0; m < MR; m++) {
        #pragma unroll
        for (int n = 0; n < NR; n++) {
            #pragma unroll
            for (int r = 0; r < 4; r++) {
                int row = rowBase + wr + m * 16 + (ln >> 4) * 4 + r;
                int col = colBase + wc + n * 16 + (ln & 15);
                if (row >= M || col >= N) continue;
                float v = acc[m][n][r];
                if constexpr (EPI == 3) {
                    v += bias[col];
                    int b = row / S_, s = row - b * S_;
                    int h = col >> 7, w = col & 127;
                    if (w < HD_)
                        kOut[((long)(b * H_ + h) * SP + s) * HD_ + w] = (bf16_t)v;
                    else
                        vtOut[((long)(b * H_ + h) * HD_ + (w - HD_)) * SP + s] = (bf16_t)v;
                } else if constexpr (EPI == 1) {
                    v += bias[col];
                    v = fmaxf(v, 0.f);
                    Cb[(long)row * ldc + col] = (bf16_t)v;
                } else {  // 5
                    Cf[(long)split * cBat + (long)row * ldc + col] = v;
                }
            }
        }
    }
}

// ---------------------------------------------------------------------------
// Fused attention: scores = (Krows @ Kall^T)*scale + G[col]; softmax; @ V.
// Grid: (128 bh, 4 row-tiles). 4 waves x 16 rows. No __syncthreads needed.
// ---------------------------------------------------------------------------
__global__ __launch_bounds__(256) void attn_fused(
    const bf16_t* __restrict__ Kb, const bf16_t* __restrict__ Vt,
    const float* __restrict__ G, const float* __restrict__ scalePtr,
    bf16_t* __restrict__ vals)
{
    __shared__ __align__(16) bf16_t Pl[4][16][232];

    const int bh = blockIdx.x;
    const int tile = blockIdx.y;
    const int wv = threadIdx.x >> 6;
    const int ln = threadIdx.x & 63;
    const int b = bh >> 3, h = bh & 7;
    const int rowBase = tile * 64 + wv * 16;

    const bf16_t* Kbh = Kb + (long)bh * SP * HD_;
    const bf16_t* Vbh = Vt + (long)bh * HD_ * SP;
    const float scale = scalePtr[0];

    const int lr = ln & 15;
    const int lk = (ln >> 4) * 8;

    // ---- phase 1: scores (14 col-frags, K = 64)
    f32x4 acc[14];
    #pragma unroll
    for (int n = 0; n < 14; n++) acc[n] = (f32x4){0.f, 0.f, 0.f, 0.f};

    int arow = rowBase + lr; arow = (arow < S_) ? arow : (S_ - 1);
    const bf16x8 a0 = *reinterpret_cast<const bf16x8*>(Kbh + (long)arow * HD_ + lk);
    const bf16x8 a1 = *reinterpret_cast<const bf16x8*>(Kbh + (long)arow * HD_ + 32 + lk);

    #pragma unroll
    for (int n = 0; n < 14; n++) {
        const bf16_t* bp = Kbh + (long)(n * 16 + lr) * HD_;
        bf16x8 b0 = *reinterpret_cast<const bf16x8*>(bp + lk);
        bf16x8 b1 = *reinterpret_cast<const bf16x8*>(bp + 32 + lk);
        acc[n] = __builtin_amdgcn_mfma_f32_16x16x32_bf16(a0, b0, acc[n], 0, 0, 0);
        acc[n] = __builtin_amdgcn_mfma_f32_16x16x32_bf16(a1, b1, acc[n], 0, 0, 0);
    }

    // ---- phase 2: softmax over 224 cols (4 rows/lane, 16-lane groups)
    float Gc[14];
    #pragma unroll
    for (int n = 0; n < 14; n++) Gc[n] = G[n * 16 + lr];

    #pragma unroll
    for (int r = 0; r < 4; r++) {
        float m = -1e30f;
        #pragma unroll
        for (int n = 0; n < 14; n++) {
            float v = acc[n][r] * scale + Gc[n];
            acc[n][r] = v;
            m = fmaxf(m, v);
        }
        #pragma unroll
        for (int off = 1; off < 16; off <<= 1) m = fmaxf(m, __shfl_xor(m, off));
        float s = 0.f;
        #pragma unroll
        for (int n = 0; n < 14; n++) {
            float e = __expf(acc[n][r] - m);
            acc[n][r] = e;
            s += e;
        }
        #pragma unroll
        for (int off = 1; off < 16; off <<= 1) s += __shfl_xor(s, off);
        float inv = 1.f / s;
        #pragma unroll
        for (int n = 0; n < 14; n++) acc[n][r] *= inv;
    }

    // ---- phase 3: P -> LDS (per-wave private)
    #pragma unroll
    for (int n = 0; n < 14; n++)
        #pragma unroll
        for (int r = 0; r < 4; r++)
            Pl[wv][(ln >> 4) * 4 + r][n * 16 + lr] = (bf16_t)acc[n][r];

    // ---- phase 4: PV (out 16 x 64, K = 224 = 7 x 32)
    f32x4 vacc[4] = {};
    #pragma unroll
    for (int kk = 0; kk < 7; kk++) {
        bf16x8 pa = *reinterpret_cast<const bf16x8*>(&Pl[wv][lr][kk * 32 + lk]);
        #pragma unroll
        for (int n = 0; n < 4; n++) {
            bf16x8 vb = *reinterpret_cast<const bf16x8*>(
                Vbh + (long)(n * 16 + lr) * SP + kk * 32 + lk);
            vacc[n] = __builtin_amdgcn_mfma_f32_16x16x32_bf16(pa, vb, vacc[n], 0, 0, 0);
        }
    }

    // ---- phase 5: write vals (B,S,D) bf16
    #pragma unroll
    for (int n = 0; n < 4; n++) {
        #pragma unroll
        for (int r = 0; r < 4; r++) {
            int row = rowBase + (ln >> 4) * 4 + r;
            if (row < S_)
                vals[((long)b * S_ + row) * D_ + h * HD_ + n * 16 + lr] =
                    (bf16_t)vacc[n][r];
        }
    }
}

// ---------------------------------------------------------------------------
// Merged preamble: f32->bf16 converts, zero K/Vt pads, G vector + scale.
// ---------------------------------------------------------------------------
__global__ __launch_bounds__(256) void prep_all(
    const float* __restrict__ x, const float* __restrict__ Wkv,
    const float* __restrict__ Wo, const float* __restrict__ W1,
    const float* __restrict__ W2, bf16_t* __restrict__ dst,
    float4* __restrict__ zeroP,
    const float* __restrict__ pos, const float* __restrict__ Wpos,
    float* __restrict__ G, float* __restrict__ scal)
{
    const int gid = blockIdx.x * blockDim.x + threadIdx.x;
    const int nthr = gridDim.x * blockDim.x;

    // converts: 1,130,496 float4-groups
    for (int i = gid; i < 1130496; i += nthr) {
        long e = (long)i * 4;
        const float* s; long off;
        if (e < 1638400)      { s = x;   off = e; }
        else if (e < 2162688) { s = Wkv; off = e - 1638400; }
        else if (e < 2424832) { s = Wo;  off = e - 2162688; }
        else if (e < 3473408) { s = W1;  off = e - 2424832; }
        else                  { s = W2;  off = e - 3473408; }
        float4 v = *reinterpret_cast<const float4*>(s + off);
        bf16x4 o = {(bf16_t)v.x, (bf16_t)v.y, (bf16_t)v.z, (bf16_t)v.w};
        *reinterpret_cast<bf16x4*>(dst + e) = o;
    }
    // zero Kb+Vt: 458,752 float4s (7,340,032 B)
    for (int i = gid; i < 458752; i += nthr)
        zeroP[i] = make_float4(0.f, 0.f, 0.f, 0.f);
    // G + scale
    if (gid < SP) {
        float g = -1e30f;
        if (gid < S_) {
            g = 0.f;
            #pragma unroll
            for (int p = 6; p < 10; p++) g += pos[(long)gid * P_ + p] * Wpos[p];
        }
        G[gid] = g;
    }
    if (gid == 0) {
        float sw = 0.f;
        for (int p = 0; p < P_; p++) sw += Wpos[p];
        scal[0] = sw * 0.125f;
    }
}

// out = LayerNorm(a + sum_p parts[p] + bias); writes f32 outf, optional bf16 outb
template <int NPART>
__global__ __launch_bounds__(256) void add_ln_p(
    const float* __restrict__ a, const float* __restrict__ parts, long partStride,
    const float* __restrict__ bias,
    const float* __restrict__ g, const float* __restrict__ beta,
    float* __restrict__ outf, bf16_t* __restrict__ outb, int rows)
{
    int row = blockIdx.x * 4 + (threadIdx.x >> 6);
    int lane = threadIdx.x & 63;
    if (row >= rows) return;
    long base = (long)row * D_;
    float v[8];
    float sum = 0.f;
    #pragma unroll
    for (int i = 0; i < 8; i++) {
        int c = lane + i * 64;
        float t = a[base + c] + bias[c];
        #pragma unroll
        for (int p = 0; p < NPART; p++) t += parts[p * partStride + base + c];
        v[i] = t;
        sum += t;
    }
    #pragma unroll
    for (int off = 32; off; off >>= 1) sum += __shfl_xor(sum, off);
    float mean = sum * (1.f / 512.f);
    float var = 0.f;
    #pragma unroll
    for (int i = 0; i < 8; i++) { float d = v[i] - mean; var += d * d; }
    #pragma unroll
    for (int off = 32; off; off >>= 1) var += __shfl_xor(var, off);
    float rstd = rsqrtf(var * (1.f / 512.f) + EPSV);
    #pragma unroll
    for (int i = 0; i < 8; i++) {
        int c = lane + i * 64;
        float o = (v[i] - mean) * rstd * g[c] + beta[c];
        outf[base + c] = o;
        if (outb) outb[base + c] = (bf16_t)o;
    }
}

extern "C" void kernel_launch(void* const* d_in, const int* in_sizes, int n_in,
                              void* d_out, int out_size, void* d_ws, size_t ws_size,
                              hipStream_t stream)
{
    const float* x    = (const float*)d_in[0];
    const float* pos  = (const float*)d_in[1];
    const float* Wkv  = (const float*)d_in[2];
    const float* bkv  = (const float*)d_in[3];
    const float* Wo   = (const float*)d_in[4];
    const float* bo   = (const float*)d_in[5];
    const float* Wpos = (const float*)d_in[6];
    const float* W1   = (const float*)d_in[8];
    const float* b1   = (const float*)d_in[9];
    const float* W2   = (const float*)d_in[10];
    const float* b2   = (const float*)d_in[11];
    const float* g1   = (const float*)d_in[12];
    const float* be1  = (const float*)d_in[13];
    const float* g2   = (const float*)d_in[14];
    const float* be2  = (const float*)d_in[15];
    float* out = (float*)d_out;

    char* w = (char*)d_ws;
    bf16_t* xb   = (bf16_t*)(w + 0);          // 3,276,800
    bf16_t* Wkvb = (bf16_t*)(w + 3276800);    // 1,048,576
    bf16_t* Wob  = (bf16_t*)(w + 4325376);    //   524,288
    bf16_t* W1b  = (bf16_t*)(w + 4849664);    // 2,097,152
    bf16_t* W2b  = (bf16_t*)(w + 6946816);    // 2,097,152
    bf16_t* Kb   = (bf16_t*)(w + 9043968);    // [128][224][64]  3,670,016
    bf16_t* Vt   = (bf16_t*)(w + 12713984);   // [128][64][224]  3,670,016
    float*  G    = (float*)(w + 16384000);    // [224]
    float*  scal = (float*)(w + 16384896);
    bf16_t* vals = (bf16_t*)(w + 16385024);   // [3200][512] bf16
    float*  hf   = (float*)(w + 19661824);    // [3200][512] f32
    bf16_t* hb   = (bf16_t*)(w + 26215424);   // [3200][512] bf16
    float*  obuf = (float*)(w + 29492224);    // 2 x [3200][512] f32
    bf16_t* tb   = (bf16_t*)(w + 42599424);   // [3200][2048] bf16
    float*  fbuf = (float*)(w + 55706624);    // 2 x [3200][512] f32

    const int M = B_ * S_;        // 3200
    const long PS = (long)M * D_; // partial stride

    // 1) merged preamble
    prep_all<<<2048, 256, 0, stream>>>(x, Wkv, Wo, W1, W2, xb, (float4*)Kb,
                                       pos, Wpos, G, scal);

    // 2) kv = x @ Wkv^T + bkv -> K [bh][224][64], V^T [bh][64][224] (400 blocks)
    mfma_gemm<128, 64, 64, 32, 3><<<dim3(16, 25, 1), 256, 0, stream>>>(
        xb, Wkvb, nullptr, nullptr, 0, 0, bkv, Kb, Vt, M, 2 * D_, D_, D_);

    // 3) fused attention -> vals bf16 (B,S,D)  (512 blocks)
    attn_fused<<<dim3(128, 4, 1), 256, 0, stream>>>(Kb, Vt, G, scal, vals);

    // 4) o partials = vals @ Wo^T, split-K x2 (400 blocks)
    mfma_gemm<128, 64, 64, 32, 5><<<dim3(8, 25, 2), 256, 0, stream>>>(
        vals, Wob, obuf, nullptr, PS, D_, nullptr, nullptr, nullptr, M, D_, D_, 256);

    // 5) h = LN(x + o0 + o1 + bo) -> hf + hb
    add_ln_p<2><<<(M + 3) / 4, 256, 0, stream>>>(x, obuf, PS, bo, g1, be1, hf, hb, M);

    // 6) t = relu(h @ W1^T + b1) -> bf16 (800 blocks)
    mfma_gemm<128, 64, 64, 32, 1><<<dim3(32, 25, 1), 256, 0, stream>>>(
        hb, W1b, nullptr, tb, 0, FF_, b1, nullptr, nullptr, M, FF_, D_, D_);

    // 7) f partials = t @ W2^T, split-K x2 (400 blocks)
    mfma_gemm<128, 64, 64, 32, 5><<<dim3(8, 25, 2), 256, 0, stream>>>(
        tb, W2b, fbuf, nullptr, PS, D_, nullptr, nullptr, nullptr, M, D_, FF_, 1024);

    // 8) out = LN(h + f0 + f1 + b2) -> f32
    add_ln_p<2><<<(M + 3) / 4, 256, 0, stream>>>(hf, fbuf, PS, b2, g2, be2, out, nullptr, M);
}

// Round 9
// 109.270 us; speedup vs baseline: 1.0669x; 1.0669x over previous
//
#include <hip/hip_runtime.h>
#include <hip/hip_bf16.h>

#define EPSV 1e-5f
static const int B_ = 16, S_ = 200, D_ = 512, H_ = 8, FF_ = 2048, P_ = 10, HD_ = 64;
static const int SP = 224;  // padded sequence length (14 x 16)

typedef __bf16 bf16_t;
typedef __attribute__((ext_vector_type(8))) __bf16 bf16x8;
typedef __attribute__((ext_vector_type(4))) __bf16 bf16x4;
typedef __attribute__((ext_vector_type(4))) float f32x4;

__device__ __forceinline__ void gload16(const void* g, void* l) {
    __builtin_amdgcn_global_load_lds(
        (const __attribute__((address_space(1))) void*)g,
        (__attribute__((address_space(3))) void*)l, 16, 0, 0);
}

// ---------------------------------------------------------------------------
// bf16 MFMA GEMM: C[M,N] = A[M,K] @ B[N,K]^T, 256 thr / 4 waves.
// BM=128, BN=64 -> wave computes 64x32 (16 MFMA per K-step).
// Double-buffered LDS + counted vmcnt(6) (round-8 core, neutral-but-kept).
// XOR source-swizzle: LDS phys chunk p of row r holds global chunk p^(r&7).
// EPI: 1 = +bias,relu -> bf16 ; 3 = +bias, scatter K/Vt bf16 (strides SP) ;
//      5 = split-K partial -> bf16 (no bias)
// ---------------------------------------------------------------------------
template <int BM, int BN, int WROWS, int WCOLS, int EPI>
__global__ __launch_bounds__(256) void mfma_gemm(
    const bf16_t* __restrict__ A,
    const bf16_t* __restrict__ Bw,
    bf16_t* __restrict__ Cb, long cBat, int ldc,
    const float* __restrict__ bias,
    bf16_t* __restrict__ kOut, bf16_t* __restrict__ vtOut,
    int M, int N, int K, int kcPerSplit)
{
    constexpr int MR = WROWS / 16, NR = WCOLS / 16;
    constexpr int NWC = BN / WCOLS;
    constexpr int NLOADS = BM / 32 + BN / 32;
    static_assert((4 / NWC) * WROWS == BM, "wave tiling must cover BM");
    static_assert(NWC * WCOLS == BN, "wave tiling must cover BN");
    static_assert(NLOADS == 6, "vmcnt literal below assumes 6 loads/stage");

    __shared__ bf16_t Asm[2][BM * 64];
    __shared__ bf16_t Bsm[2][BN * 64];

    const int wv = threadIdx.x >> 6;
    const int ln = threadIdx.x & 63;
    const int split = blockIdx.z;
    const int rowBase = blockIdx.y * BM;
    const int colBase = blockIdx.x * BN;
    const int wr = (wv / NWC) * WROWS;
    const int wc = (wv % NWC) * WCOLS;

    const int lr8 = ln >> 3;               // row within 8-row group
    const int csw = ((ln & 7) ^ lr8) * 8;  // swizzled source chunk offset

    f32x4 acc[MR][NR] = {};

    const int kBeg = split * kcPerSplit;
    const int kEnd = kBeg + kcPerSplit;

    auto STAGE = [&](int k0, int buf) {
        #pragma unroll
        for (int i = 0; i < BM / 32; i++) {
            int row = i * 32 + wv * 8 + lr8;
            int gr = rowBase + row; gr = (gr < M) ? gr : (M - 1);
            gload16(A + (long)gr * K + k0 + csw, &Asm[buf][(i * 32 + wv * 8) * 64]);
        }
        #pragma unroll
        for (int i = 0; i < BN / 32; i++) {
            int col = i * 32 + wv * 8 + lr8;
            int gc = colBase + col; gc = (gc < N) ? gc : (N - 1);
            gload16(Bw + (long)gc * K + k0 + csw, &Bsm[buf][(i * 32 + wv * 8) * 64]);
        }
    };

    auto COMPUTE = [&](int buf) {
        #pragma unroll
        for (int kk = 0; kk < 2; kk++) {
            bf16x8 af[MR], bfr[NR];
            #pragma unroll
            for (int m = 0; m < MR; m++) {
                int r = wr + m * 16 + (ln & 15);
                int pc = (kk * 4 + (ln >> 4)) ^ (r & 7);
                af[m] = *reinterpret_cast<const bf16x8*>(&Asm[buf][r * 64 + pc * 8]);
            }
            #pragma unroll
            for (int n = 0; n < NR; n++) {
                int r = wc + n * 16 + (ln & 15);
                int pc = (kk * 4 + (ln >> 4)) ^ (r & 7);
                bfr[n] = *reinterpret_cast<const bf16x8*>(&Bsm[buf][r * 64 + pc * 8]);
            }
            #pragma unroll
            for (int m = 0; m < MR; m++)
                #pragma unroll
                for (int n = 0; n < NR; n++)
                    acc[m][n] = __builtin_amdgcn_mfma_f32_16x16x32_bf16(
                        af[m], bfr[n], acc[m][n], 0, 0, 0);
        }
    };

    STAGE(kBeg, 0);

    int t = 0;
    for (int k0 = kBeg; k0 < kEnd; k0 += 64, ++t) {
        const bool has_next = (k0 + 64 < kEnd);
        if (has_next) {
            STAGE(k0 + 64, (t + 1) & 1);
            asm volatile("s_waitcnt vmcnt(6)" ::: "memory");
        } else {
            asm volatile("s_waitcnt vmcnt(0)" ::: "memory");
        }
        __builtin_amdgcn_s_barrier();
        __builtin_amdgcn_sched_barrier(0);
        COMPUTE(t & 1);
        if (has_next) {
            __builtin_amdgcn_sched_barrier(0);
            __builtin_amdgcn_s_barrier();
        }
    }

    #pragma unroll
    for (int m = 0; m < MR; m++) {
        #pragma unroll
        for (int n = 0; n < NR; n++) {
            #pragma unroll
            for (int r = 0; r < 4; r++) {
                int row = rowBase + wr + m * 16 + (ln >> 4) * 4 + r;
                int col = colBase + wc + n * 16 + (ln & 15);
                if (row >= M || col >= N) continue;
                float v = acc[m][n][r];
                if constexpr (EPI == 3) {
                    v += bias[col];
                    int b = row / S_, s = row - b * S_;
                    int h = col >> 7, w = col & 127;
                    if (w < HD_)
                        kOut[((long)(b * H_ + h) * SP + s) * HD_ + w] = (bf16_t)v;
                    else
                        vtOut[((long)(b * H_ + h) * HD_ + (w - HD_)) * SP + s] = (bf16_t)v;
                } else if constexpr (EPI == 1) {
                    v += bias[col];
                    v = fmaxf(v, 0.f);
                    Cb[(long)row * ldc + col] = (bf16_t)v;
                } else {  // 5: bf16 split-K partial
                    Cb[(long)split * cBat + (long)row * ldc + col] = (bf16_t)v;
                }
            }
        }
    }
}

// ---------------------------------------------------------------------------
// Fused attention: scores = (Krows @ Kall^T)*scale + G[col]; softmax; @ V.
// Grid: (128 bh, 4 row-tiles). 4 waves x 16 rows. No __syncthreads needed.
// ---------------------------------------------------------------------------
__global__ __launch_bounds__(256) void attn_fused(
    const bf16_t* __restrict__ Kb, const bf16_t* __restrict__ Vt,
    const float* __restrict__ G, const float* __restrict__ scalePtr,
    bf16_t* __restrict__ vals)
{
    __shared__ __align__(16) bf16_t Pl[4][16][232];

    const int bh = blockIdx.x;
    const int tile = blockIdx.y;
    const int wv = threadIdx.x >> 6;
    const int ln = threadIdx.x & 63;
    const int b = bh >> 3, h = bh & 7;
    const int rowBase = tile * 64 + wv * 16;

    const bf16_t* Kbh = Kb + (long)bh * SP * HD_;
    const bf16_t* Vbh = Vt + (long)bh * HD_ * SP;
    const float scale = scalePtr[0];

    const int lr = ln & 15;
    const int lk = (ln >> 4) * 8;

    // ---- phase 1: scores (14 col-frags, K = 64)
    f32x4 acc[14];
    #pragma unroll
    for (int n = 0; n < 14; n++) acc[n] = (f32x4){0.f, 0.f, 0.f, 0.f};

    int arow = rowBase + lr; arow = (arow < S_) ? arow : (S_ - 1);
    const bf16x8 a0 = *reinterpret_cast<const bf16x8*>(Kbh + (long)arow * HD_ + lk);
    const bf16x8 a1 = *reinterpret_cast<const bf16x8*>(Kbh + (long)arow * HD_ + 32 + lk);

    #pragma unroll
    for (int n = 0; n < 14; n++) {
        const bf16_t* bp = Kbh + (long)(n * 16 + lr) * HD_;
        bf16x8 b0 = *reinterpret_cast<const bf16x8*>(bp + lk);
        bf16x8 b1 = *reinterpret_cast<const bf16x8*>(bp + 32 + lk);
        acc[n] = __builtin_amdgcn_mfma_f32_16x16x32_bf16(a0, b0, acc[n], 0, 0, 0);
        acc[n] = __builtin_amdgcn_mfma_f32_16x16x32_bf16(a1, b1, acc[n], 0, 0, 0);
    }

    // ---- phase 2: softmax over 224 cols (4 rows/lane, 16-lane groups)
    float Gc[14];
    #pragma unroll
    for (int n = 0; n < 14; n++) Gc[n] = G[n * 16 + lr];

    #pragma unroll
    for (int r = 0; r < 4; r++) {
        float m = -1e30f;
        #pragma unroll
        for (int n = 0; n < 14; n++) {
            float v = acc[n][r] * scale + Gc[n];
            acc[n][r] = v;
            m = fmaxf(m, v);
        }
        #pragma unroll
        for (int off = 1; off < 16; off <<= 1) m = fmaxf(m, __shfl_xor(m, off));
        float s = 0.f;
        #pragma unroll
        for (int n = 0; n < 14; n++) {
            float e = __expf(acc[n][r] - m);
            acc[n][r] = e;
            s += e;
        }
        #pragma unroll
        for (int off = 1; off < 16; off <<= 1) s += __shfl_xor(s, off);
        float inv = 1.f / s;
        #pragma unroll
        for (int n = 0; n < 14; n++) acc[n][r] *= inv;
    }

    // ---- phase 3: P -> LDS (per-wave private)
    #pragma unroll
    for (int n = 0; n < 14; n++)
        #pragma unroll
        for (int r = 0; r < 4; r++)
            Pl[wv][(ln >> 4) * 4 + r][n * 16 + lr] = (bf16_t)acc[n][r];

    // ---- phase 4: PV (out 16 x 64, K = 224 = 7 x 32)
    f32x4 vacc[4] = {};
    #pragma unroll
    for (int kk = 0; kk < 7; kk++) {
        bf16x8 pa = *reinterpret_cast<const bf16x8*>(&Pl[wv][lr][kk * 32 + lk]);
        #pragma unroll
        for (int n = 0; n < 4; n++) {
            bf16x8 vb = *reinterpret_cast<const bf16x8*>(
                Vbh + (long)(n * 16 + lr) * SP + kk * 32 + lk);
            vacc[n] = __builtin_amdgcn_mfma_f32_16x16x32_bf16(pa, vb, vacc[n], 0, 0, 0);
        }
    }

    // ---- phase 5: write vals (B,S,D) bf16
    #pragma unroll
    for (int n = 0; n < 4; n++) {
        #pragma unroll
        for (int r = 0; r < 4; r++) {
            int row = rowBase + (ln >> 4) * 4 + r;
            if (row < S_)
                vals[((long)b * S_ + row) * D_ + h * HD_ + n * 16 + lr] =
                    (bf16_t)vacc[n][r];
        }
    }
}

// ---------------------------------------------------------------------------
// Merged preamble: f32->bf16 converts, zero K/Vt pads, G vector + scale.
// ---------------------------------------------------------------------------
__global__ __launch_bounds__(256) void prep_all(
    const float* __restrict__ x, const float* __restrict__ Wkv,
    const float* __restrict__ Wo, const float* __restrict__ W1,
    const float* __restrict__ W2, bf16_t* __restrict__ dst,
    float4* __restrict__ zeroP,
    const float* __restrict__ pos, const float* __restrict__ Wpos,
    float* __restrict__ G, float* __restrict__ scal)
{
    const int gid = blockIdx.x * blockDim.x + threadIdx.x;
    const int nthr = gridDim.x * blockDim.x;

    // converts: 1,130,496 float4-groups
    for (int i = gid; i < 1130496; i += nthr) {
        long e = (long)i * 4;
        const float* s; long off;
        if (e < 1638400)      { s = x;   off = e; }
        else if (e < 2162688) { s = Wkv; off = e - 1638400; }
        else if (e < 2424832) { s = Wo;  off = e - 2162688; }
        else if (e < 3473408) { s = W1;  off = e - 2424832; }
        else                  { s = W2;  off = e - 3473408; }
        float4 v = *reinterpret_cast<const float4*>(s + off);
        bf16x4 o = {(bf16_t)v.x, (bf16_t)v.y, (bf16_t)v.z, (bf16_t)v.w};
        *reinterpret_cast<bf16x4*>(dst + e) = o;
    }
    // zero Kb+Vt: 458,752 float4s (7,340,032 B)
    for (int i = gid; i < 458752; i += nthr)
        zeroP[i] = make_float4(0.f, 0.f, 0.f, 0.f);
    // G + scale
    if (gid < SP) {
        float g = -1e30f;
        if (gid < S_) {
            g = 0.f;
            #pragma unroll
            for (int p = 6; p < 10; p++) g += pos[(long)gid * P_ + p] * Wpos[p];
        }
        G[gid] = g;
    }
    if (gid == 0) {
        float sw = 0.f;
        for (int p = 0; p < P_; p++) sw += Wpos[p];
        scal[0] = sw * 0.125f;
    }
}

// ---------------------------------------------------------------------------
// Vectorized add+LN: out = LayerNorm(a + sum_p parts[p] + bias).
// One wave per 512-col row; lane owns 8 contiguous cols (bf16x8/float4 loads).
// a, parts are bf16. F32OUT: write f32 outf, else bf16 outb.
// ---------------------------------------------------------------------------
template <int NPART, bool F32OUT>
__global__ __launch_bounds__(256) void add_ln_v(
    const bf16_t* __restrict__ a, const bf16_t* __restrict__ parts, long partStride,
    const float* __restrict__ bias,
    const float* __restrict__ g, const float* __restrict__ beta,
    float* __restrict__ outf, bf16_t* __restrict__ outb, int rows)
{
    int row = blockIdx.x * 4 + (threadIdx.x >> 6);
    int lane = threadIdx.x & 63;
    if (row >= rows) return;
    const int col = lane * 8;
    const long base = (long)row * D_ + col;

    bf16x8 a8 = *reinterpret_cast<const bf16x8*>(a + base);
    float4 b0 = *reinterpret_cast<const float4*>(bias + col);
    float4 b1 = *reinterpret_cast<const float4*>(bias + col + 4);
    const float bb[8] = {b0.x, b0.y, b0.z, b0.w, b1.x, b1.y, b1.z, b1.w};

    bf16x8 p8[NPART];
    #pragma unroll
    for (int p = 0; p < NPART; p++)
        p8[p] = *reinterpret_cast<const bf16x8*>(parts + (long)p * partStride + base);

    float v[8];
    float sum = 0.f;
    #pragma unroll
    for (int i = 0; i < 8; i++) {
        float t = (float)a8[i] + bb[i];
        #pragma unroll
        for (int p = 0; p < NPART; p++) t += (float)p8[p][i];
        v[i] = t;
        sum += t;
    }
    #pragma unroll
    for (int off = 32; off; off >>= 1) sum += __shfl_xor(sum, off);
    float mean = sum * (1.f / 512.f);
    float var = 0.f;
    #pragma unroll
    for (int i = 0; i < 8; i++) { float d = v[i] - mean; var += d * d; }
    #pragma unroll
    for (int off = 32; off; off >>= 1) var += __shfl_xor(var, off);
    float rstd = rsqrtf(var * (1.f / 512.f) + EPSV);

    float4 g0 = *reinterpret_cast<const float4*>(g + col);
    float4 g1v = *reinterpret_cast<const float4*>(g + col + 4);
    float4 e0 = *reinterpret_cast<const float4*>(beta + col);
    float4 e1 = *reinterpret_cast<const float4*>(beta + col + 4);
    const float gg[8] = {g0.x, g0.y, g0.z, g0.w, g1v.x, g1v.y, g1v.z, g1v.w};
    const float ee[8] = {e0.x, e0.y, e0.z, e0.w, e1.x, e1.y, e1.z, e1.w};

    if constexpr (F32OUT) {
        float4 o0, o1;
        o0.x = (v[0]-mean)*rstd*gg[0]+ee[0]; o0.y = (v[1]-mean)*rstd*gg[1]+ee[1];
        o0.z = (v[2]-mean)*rstd*gg[2]+ee[2]; o0.w = (v[3]-mean)*rstd*gg[3]+ee[3];
        o1.x = (v[4]-mean)*rstd*gg[4]+ee[4]; o1.y = (v[5]-mean)*rstd*gg[5]+ee[5];
        o1.z = (v[6]-mean)*rstd*gg[6]+ee[6]; o1.w = (v[7]-mean)*rstd*gg[7]+ee[7];
        *reinterpret_cast<float4*>(outf + base) = o0;
        *reinterpret_cast<float4*>(outf + base + 4) = o1;
    } else {
        bf16x8 o8;
        #pragma unroll
        for (int i = 0; i < 8; i++)
            o8[i] = (bf16_t)((v[i] - mean) * rstd * gg[i] + ee[i]);
        *reinterpret_cast<bf16x8*>(outb + base) = o8;
    }
}

extern "C" void kernel_launch(void* const* d_in, const int* in_sizes, int n_in,
                              void* d_out, int out_size, void* d_ws, size_t ws_size,
                              hipStream_t stream)
{
    const float* x    = (const float*)d_in[0];
    const float* pos  = (const float*)d_in[1];
    const float* Wkv  = (const float*)d_in[2];
    const float* bkv  = (const float*)d_in[3];
    const float* Wo   = (const float*)d_in[4];
    const float* bo   = (const float*)d_in[5];
    const float* Wpos = (const float*)d_in[6];
    const float* W1   = (const float*)d_in[8];
    const float* b1   = (const float*)d_in[9];
    const float* W2   = (const float*)d_in[10];
    const float* b2   = (const float*)d_in[11];
    const float* g1   = (const float*)d_in[12];
    const float* be1  = (const float*)d_in[13];
    const float* g2   = (const float*)d_in[14];
    const float* be2  = (const float*)d_in[15];
    float* out = (float*)d_out;

    char* w = (char*)d_ws;
    bf16_t* xb     = (bf16_t*)(w + 0);          // 3,276,800
    bf16_t* Wkvb   = (bf16_t*)(w + 3276800);    // 1,048,576
    bf16_t* Wob    = (bf16_t*)(w + 4325376);    //   524,288
    bf16_t* W1b    = (bf16_t*)(w + 4849664);    // 2,097,152
    bf16_t* W2b    = (bf16_t*)(w + 6946816);    // 2,097,152
    bf16_t* Kb     = (bf16_t*)(w + 9043968);    // [128][224][64]  3,670,016
    bf16_t* Vt     = (bf16_t*)(w + 12713984);   // [128][64][224]  3,670,016
    float*  G      = (float*)(w + 16384000);    // [224]
    float*  scal   = (float*)(w + 16384896);
    bf16_t* vals   = (bf16_t*)(w + 16385024);   // [3200][512] bf16
    bf16_t* hb     = (bf16_t*)(w + 19661824);   // [3200][512] bf16
    bf16_t* obuf_b = (bf16_t*)(w + 22938624);   // 2 x [3200][512] bf16 partials
    bf16_t* tb     = (bf16_t*)(w + 29492224);   // [3200][2048] bf16
    bf16_t* fbuf_b = (bf16_t*)(w + 42599424);   // 2 x [3200][512] bf16 partials

    const int M = B_ * S_;        // 3200
    const long PS = (long)M * D_; // partial stride (elements)

    // 1) merged preamble
    prep_all<<<2048, 256, 0, stream>>>(x, Wkv, Wo, W1, W2, xb, (float4*)Kb,
                                       pos, Wpos, G, scal);

    // 2) kv = x @ Wkv^T + bkv -> K [bh][224][64], V^T [bh][64][224] (400 blocks)
    mfma_gemm<128, 64, 64, 32, 3><<<dim3(16, 25, 1), 256, 0, stream>>>(
        xb, Wkvb, nullptr, 0, 0, bkv, Kb, Vt, M, 2 * D_, D_, D_);

    // 3) fused attention -> vals bf16 (B,S,D)  (512 blocks)
    attn_fused<<<dim3(128, 4, 1), 256, 0, stream>>>(Kb, Vt, G, scal, vals);

    // 4) o partials (bf16) = vals @ Wo^T, split-K x2 (400 blocks)
    mfma_gemm<128, 64, 64, 32, 5><<<dim3(8, 25, 2), 256, 0, stream>>>(
        vals, Wob, obuf_b, PS, D_, nullptr, nullptr, nullptr, M, D_, D_, 256);

    // 5) h = LN(xb + o0 + o1 + bo) -> hb bf16 (vectorized)
    add_ln_v<2, false><<<(M + 3) / 4, 256, 0, stream>>>(
        xb, obuf_b, PS, bo, g1, be1, nullptr, hb, M);

    // 6) t = relu(h @ W1^T + b1) -> bf16 (800 blocks)
    mfma_gemm<128, 64, 64, 32, 1><<<dim3(32, 25, 1), 256, 0, stream>>>(
        hb, W1b, tb, 0, FF_, b1, nullptr, nullptr, M, FF_, D_, D_);

    // 7) f partials (bf16) = t @ W2^T, split-K x2 (400 blocks)
    mfma_gemm<128, 64, 64, 32, 5><<<dim3(8, 25, 2), 256, 0, stream>>>(
        tb, W2b, fbuf_b, PS, D_, nullptr, nullptr, nullptr, M, D_, FF_, 1024);

    // 8) out = LN(hb + f0 + f1 + b2) -> f32 (vectorized)
    add_ln_v<2, true><<<(M + 3) / 4, 256, 0, stream>>>(
        hb, fbuf_b, PS, b2, g2, be2, out, nullptr, M);
}

// Round 10
// 104.065 us; speedup vs baseline: 1.1202x; 1.0500x over previous
//
#include <hip/hip_runtime.h>
#include <hip/hip_bf16.h>

#define EPSV 1e-5f
static const int B_ = 16, S_ = 200, D_ = 512, H_ = 8, FF_ = 2048, P_ = 10, HD_ = 64;
static const int SP = 224;  // padded sequence length (14 x 16)

typedef __bf16 bf16_t;
typedef __attribute__((ext_vector_type(8))) __bf16 bf16x8;
typedef __attribute__((ext_vector_type(4))) __bf16 bf16x4;
typedef __attribute__((ext_vector_type(4))) float f32x4;

__device__ __forceinline__ void gload16(const void* g, void* l) {
    __builtin_amdgcn_global_load_lds(
        (const __attribute__((address_space(1))) void*)g,
        (__attribute__((address_space(3))) void*)l, 16, 0, 0);
}

// ---------------------------------------------------------------------------
// bf16 MFMA GEMM: C[M,N] = A[M,K] @ B[N,K]^T, 256 thr / 4 waves.
// Single-buffer LDS, 2-barrier K-loop (best-measured core, R7 A/B).
// XOR source-swizzle kept: LDS phys chunk p of row r holds global chunk
// p ^ (r&7); readers apply the same XOR (bank-conflict-free ds_read_b128).
// Tiles: 128x64 (waves 2x1 of 64x32, 16 MFMA/step) or 128x128 (waves 2x2
// of 64x64, 32 MFMA/step, ff1).
// EPI: 1 = +bias,relu -> bf16 ; 3 = +bias, scatter K/Vt bf16 (strides SP) ;
//      5 = split-K partial -> bf16 (no bias)
// ---------------------------------------------------------------------------
template <int BM, int BN, int WROWS, int WCOLS, int EPI>
__global__ __launch_bounds__(256) void mfma_gemm(
    const bf16_t* __restrict__ A,
    const bf16_t* __restrict__ Bw,
    bf16_t* __restrict__ Cb, long cBat, int ldc,
    const float* __restrict__ bias,
    bf16_t* __restrict__ kOut, bf16_t* __restrict__ vtOut,
    int M, int N, int K, int kcPerSplit)
{
    constexpr int MR = WROWS / 16, NR = WCOLS / 16;
    constexpr int NWC = BN / WCOLS;
    static_assert((4 / NWC) * WROWS == BM, "wave tiling must cover BM");
    static_assert(NWC * WCOLS == BN, "wave tiling must cover BN");

    __shared__ bf16_t Asm[BM * 64];
    __shared__ bf16_t Bsm[BN * 64];

    const int wv = threadIdx.x >> 6;
    const int ln = threadIdx.x & 63;
    const int split = blockIdx.z;
    const int rowBase = blockIdx.y * BM;
    const int colBase = blockIdx.x * BN;
    const int wr = (wv / NWC) * WROWS;
    const int wc = (wv % NWC) * WCOLS;

    const int lr8 = ln >> 3;               // row within 8-row group
    const int csw = ((ln & 7) ^ lr8) * 8;  // swizzled source chunk offset

    f32x4 acc[MR][NR] = {};

    const int kBeg = split * kcPerSplit;
    const int kEnd = kBeg + kcPerSplit;

    for (int k0 = kBeg; k0 < kEnd; k0 += 64) {
        #pragma unroll
        for (int i = 0; i < BM / 32; i++) {
            int row = i * 32 + wv * 8 + lr8;
            int gr = rowBase + row; gr = (gr < M) ? gr : (M - 1);
            gload16(A + (long)gr * K + k0 + csw, &Asm[(i * 32 + wv * 8) * 64]);
        }
        #pragma unroll
        for (int i = 0; i < BN / 32; i++) {
            int col = i * 32 + wv * 8 + lr8;
            int gc = colBase + col; gc = (gc < N) ? gc : (N - 1);
            gload16(Bw + (long)gc * K + k0 + csw, &Bsm[(i * 32 + wv * 8) * 64]);
        }
        __syncthreads();  // drains vmcnt -> LDS valid

        #pragma unroll
        for (int kk = 0; kk < 2; kk++) {
            bf16x8 af[MR], bfr[NR];
            #pragma unroll
            for (int m = 0; m < MR; m++) {
                int r = wr + m * 16 + (ln & 15);
                int pc = (kk * 4 + (ln >> 4)) ^ (r & 7);
                af[m] = *reinterpret_cast<const bf16x8*>(&Asm[r * 64 + pc * 8]);
            }
            #pragma unroll
            for (int n = 0; n < NR; n++) {
                int r = wc + n * 16 + (ln & 15);
                int pc = (kk * 4 + (ln >> 4)) ^ (r & 7);
                bfr[n] = *reinterpret_cast<const bf16x8*>(&Bsm[r * 64 + pc * 8]);
            }
            #pragma unroll
            for (int m = 0; m < MR; m++)
                #pragma unroll
                for (int n = 0; n < NR; n++)
                    acc[m][n] = __builtin_amdgcn_mfma_f32_16x16x32_bf16(
                        af[m], bfr[n], acc[m][n], 0, 0, 0);
        }
        __syncthreads();
    }

    #pragma unroll
    for (int m = 0; m < MR; m++) {
        #pragma unroll
        for (int n = 0; n < NR; n++) {
            #pragma unroll
            for (int r = 0; r < 4; r++) {
                int row = rowBase + wr + m * 16 + (ln >> 4) * 4 + r;
                int col = colBase + wc + n * 16 + (ln & 15);
                if (row >= M || col >= N) continue;
                float v = acc[m][n][r];
                if constexpr (EPI == 3) {
                    v += bias[col];
                    int b = row / S_, s = row - b * S_;
                    int h = col >> 7, w = col & 127;
                    if (w < HD_)
                        kOut[((long)(b * H_ + h) * SP + s) * HD_ + w] = (bf16_t)v;
                    else
                        vtOut[((long)(b * H_ + h) * HD_ + (w - HD_)) * SP + s] = (bf16_t)v;
                } else if constexpr (EPI == 1) {
                    v += bias[col];
                    v = fmaxf(v, 0.f);
                    Cb[(long)row * ldc + col] = (bf16_t)v;
                } else {  // 5: bf16 split-K partial
                    Cb[(long)split * cBat + (long)row * ldc + col] = (bf16_t)v;
                }
            }
        }
    }
}

// ---------------------------------------------------------------------------
// Fused attention: scores = (Krows @ Kall^T)*scale + G[col]; softmax; @ V.
// Grid: (128 bh, 4 row-tiles). 4 waves x 16 rows. No __syncthreads needed.
// ---------------------------------------------------------------------------
__global__ __launch_bounds__(256) void attn_fused(
    const bf16_t* __restrict__ Kb, const bf16_t* __restrict__ Vt,
    const float* __restrict__ G, const float* __restrict__ scalePtr,
    bf16_t* __restrict__ vals)
{
    __shared__ __align__(16) bf16_t Pl[4][16][232];

    const int bh = blockIdx.x;
    const int tile = blockIdx.y;
    const int wv = threadIdx.x >> 6;
    const int ln = threadIdx.x & 63;
    const int b = bh >> 3, h = bh & 7;
    const int rowBase = tile * 64 + wv * 16;

    const bf16_t* Kbh = Kb + (long)bh * SP * HD_;
    const bf16_t* Vbh = Vt + (long)bh * HD_ * SP;
    const float scale = scalePtr[0];

    const int lr = ln & 15;
    const int lk = (ln >> 4) * 8;

    // ---- phase 1: scores (14 col-frags, K = 64)
    f32x4 acc[14];
    #pragma unroll
    for (int n = 0; n < 14; n++) acc[n] = (f32x4){0.f, 0.f, 0.f, 0.f};

    int arow = rowBase + lr; arow = (arow < S_) ? arow : (S_ - 1);
    const bf16x8 a0 = *reinterpret_cast<const bf16x8*>(Kbh + (long)arow * HD_ + lk);
    const bf16x8 a1 = *reinterpret_cast<const bf16x8*>(Kbh + (long)arow * HD_ + 32 + lk);

    #pragma unroll
    for (int n = 0; n < 14; n++) {
        const bf16_t* bp = Kbh + (long)(n * 16 + lr) * HD_;
        bf16x8 b0 = *reinterpret_cast<const bf16x8*>(bp + lk);
        bf16x8 b1 = *reinterpret_cast<const bf16x8*>(bp + 32 + lk);
        acc[n] = __builtin_amdgcn_mfma_f32_16x16x32_bf16(a0, b0, acc[n], 0, 0, 0);
        acc[n] = __builtin_amdgcn_mfma_f32_16x16x32_bf16(a1, b1, acc[n], 0, 0, 0);
    }

    // ---- phase 2: softmax over 224 cols (4 rows/lane, 16-lane groups)
    float Gc[14];
    #pragma unroll
    for (int n = 0; n < 14; n++) Gc[n] = G[n * 16 + lr];

    #pragma unroll
    for (int r = 0; r < 4; r++) {
        float m = -1e30f;
        #pragma unroll
        for (int n = 0; n < 14; n++) {
            float v = acc[n][r] * scale + Gc[n];
            acc[n][r] = v;
            m = fmaxf(m, v);
        }
        #pragma unroll
        for (int off = 1; off < 16; off <<= 1) m = fmaxf(m, __shfl_xor(m, off));
        float s = 0.f;
        #pragma unroll
        for (int n = 0; n < 14; n++) {
            float e = __expf(acc[n][r] - m);
            acc[n][r] = e;
            s += e;
        }
        #pragma unroll
        for (int off = 1; off < 16; off <<= 1) s += __shfl_xor(s, off);
        float inv = 1.f / s;
        #pragma unroll
        for (int n = 0; n < 14; n++) acc[n][r] *= inv;
    }

    // ---- phase 3: P -> LDS (per-wave private)
    #pragma unroll
    for (int n = 0; n < 14; n++)
        #pragma unroll
        for (int r = 0; r < 4; r++)
            Pl[wv][(ln >> 4) * 4 + r][n * 16 + lr] = (bf16_t)acc[n][r];

    // ---- phase 4: PV (out 16 x 64, K = 224 = 7 x 32)
    f32x4 vacc[4] = {};
    #pragma unroll
    for (int kk = 0; kk < 7; kk++) {
        bf16x8 pa = *reinterpret_cast<const bf16x8*>(&Pl[wv][lr][kk * 32 + lk]);
        #pragma unroll
        for (int n = 0; n < 4; n++) {
            bf16x8 vb = *reinterpret_cast<const bf16x8*>(
                Vbh + (long)(n * 16 + lr) * SP + kk * 32 + lk);
            vacc[n] = __builtin_amdgcn_mfma_f32_16x16x32_bf16(pa, vb, vacc[n], 0, 0, 0);
        }
    }

    // ---- phase 5: write vals (B,S,D) bf16
    #pragma unroll
    for (int n = 0; n < 4; n++) {
        #pragma unroll
        for (int r = 0; r < 4; r++) {
            int row = rowBase + (ln >> 4) * 4 + r;
            if (row < S_)
                vals[((long)b * S_ + row) * D_ + h * HD_ + n * 16 + lr] =
                    (bf16_t)vacc[n][r];
        }
    }
}

// ---------------------------------------------------------------------------
// Merged preamble: f32->bf16 converts, zero K/Vt pads, G vector + scale.
// ---------------------------------------------------------------------------
__global__ __launch_bounds__(256) void prep_all(
    const float* __restrict__ x, const float* __restrict__ Wkv,
    const float* __restrict__ Wo, const float* __restrict__ W1,
    const float* __restrict__ W2, bf16_t* __restrict__ dst,
    float4* __restrict__ zeroP,
    const float* __restrict__ pos, const float* __restrict__ Wpos,
    float* __restrict__ G, float* __restrict__ scal)
{
    const int gid = blockIdx.x * blockDim.x + threadIdx.x;
    const int nthr = gridDim.x * blockDim.x;

    // converts: 1,130,496 float4-groups
    for (int i = gid; i < 1130496; i += nthr) {
        long e = (long)i * 4;
        const float* s; long off;
        if (e < 1638400)      { s = x;   off = e; }
        else if (e < 2162688) { s = Wkv; off = e - 1638400; }
        else if (e < 2424832) { s = Wo;  off = e - 2162688; }
        else if (e < 3473408) { s = W1;  off = e - 2424832; }
        else                  { s = W2;  off = e - 3473408; }
        float4 v = *reinterpret_cast<const float4*>(s + off);
        bf16x4 o = {(bf16_t)v.x, (bf16_t)v.y, (bf16_t)v.z, (bf16_t)v.w};
        *reinterpret_cast<bf16x4*>(dst + e) = o;
    }
    // zero Kb+Vt: 458,752 float4s (7,340,032 B)
    for (int i = gid; i < 458752; i += nthr)
        zeroP[i] = make_float4(0.f, 0.f, 0.f, 0.f);
    // G + scale
    if (gid < SP) {
        float g = -1e30f;
        if (gid < S_) {
            g = 0.f;
            #pragma unroll
            for (int p = 6; p < 10; p++) g += pos[(long)gid * P_ + p] * Wpos[p];
        }
        G[gid] = g;
    }
    if (gid == 0) {
        float sw = 0.f;
        for (int p = 0; p < P_; p++) sw += Wpos[p];
        scal[0] = sw * 0.125f;
    }
}

// ---------------------------------------------------------------------------
// Vectorized add+LN: out = LayerNorm(a + sum_p parts[p] + bias).
// One wave per 512-col row; lane owns 8 contiguous cols (bf16x8/float4 loads).
// ---------------------------------------------------------------------------
template <int NPART, bool F32OUT>
__global__ __launch_bounds__(256) void add_ln_v(
    const bf16_t* __restrict__ a, const bf16_t* __restrict__ parts, long partStride,
    const float* __restrict__ bias,
    const float* __restrict__ g, const float* __restrict__ beta,
    float* __restrict__ outf, bf16_t* __restrict__ outb, int rows)
{
    int row = blockIdx.x * 4 + (threadIdx.x >> 6);
    int lane = threadIdx.x & 63;
    if (row >= rows) return;
    const int col = lane * 8;
    const long base = (long)row * D_ + col;

    bf16x8 a8 = *reinterpret_cast<const bf16x8*>(a + base);
    float4 b0 = *reinterpret_cast<const float4*>(bias + col);
    float4 b1 = *reinterpret_cast<const float4*>(bias + col + 4);
    const float bb[8] = {b0.x, b0.y, b0.z, b0.w, b1.x, b1.y, b1.z, b1.w};

    bf16x8 p8[NPART];
    #pragma unroll
    for (int p = 0; p < NPART; p++)
        p8[p] = *reinterpret_cast<const bf16x8*>(parts + (long)p * partStride + base);

    float v[8];
    float sum = 0.f;
    #pragma unroll
    for (int i = 0; i < 8; i++) {
        float t = (float)a8[i] + bb[i];
        #pragma unroll
        for (int p = 0; p < NPART; p++) t += (float)p8[p][i];
        v[i] = t;
        sum += t;
    }
    #pragma unroll
    for (int off = 32; off; off >>= 1) sum += __shfl_xor(sum, off);
    float mean = sum * (1.f / 512.f);
    float var = 0.f;
    #pragma unroll
    for (int i = 0; i < 8; i++) { float d = v[i] - mean; var += d * d; }
    #pragma unroll
    for (int off = 32; off; off >>= 1) var += __shfl_xor(var, off);
    float rstd = rsqrtf(var * (1.f / 512.f) + EPSV);

    float4 g0 = *reinterpret_cast<const float4*>(g + col);
    float4 g1v = *reinterpret_cast<const float4*>(g + col + 4);
    float4 e0 = *reinterpret_cast<const float4*>(beta + col);
    float4 e1 = *reinterpret_cast<const float4*>(beta + col + 4);
    const float gg[8] = {g0.x, g0.y, g0.z, g0.w, g1v.x, g1v.y, g1v.z, g1v.w};
    const float ee[8] = {e0.x, e0.y, e0.z, e0.w, e1.x, e1.y, e1.z, e1.w};

    if constexpr (F32OUT) {
        float4 o0, o1;
        o0.x = (v[0]-mean)*rstd*gg[0]+ee[0]; o0.y = (v[1]-mean)*rstd*gg[1]+ee[1];
        o0.z = (v[2]-mean)*rstd*gg[2]+ee[2]; o0.w = (v[3]-mean)*rstd*gg[3]+ee[3];
        o1.x = (v[4]-mean)*rstd*gg[4]+ee[4]; o1.y = (v[5]-mean)*rstd*gg[5]+ee[5];
        o1.z = (v[6]-mean)*rstd*gg[6]+ee[6]; o1.w = (v[7]-mean)*rstd*gg[7]+ee[7];
        *reinterpret_cast<float4*>(outf + base) = o0;
        *reinterpret_cast<float4*>(outf + base + 4) = o1;
    } else {
        bf16x8 o8;
        #pragma unroll
        for (int i = 0; i < 8; i++)
            o8[i] = (bf16_t)((v[i] - mean) * rstd * gg[i] + ee[i]);
        *reinterpret_cast<bf16x8*>(outb + base) = o8;
    }
}

extern "C" void kernel_launch(void* const* d_in, const int* in_sizes, int n_in,
                              void* d_out, int out_size, void* d_ws, size_t ws_size,
                              hipStream_t stream)
{
    const float* x    = (const float*)d_in[0];
    const float* pos  = (const float*)d_in[1];
    const float* Wkv  = (const float*)d_in[2];
    const float* bkv  = (const float*)d_in[3];
    const float* Wo   = (const float*)d_in[4];
    const float* bo   = (const float*)d_in[5];
    const float* Wpos = (const float*)d_in[6];
    const float* W1   = (const float*)d_in[8];
    const float* b1   = (const float*)d_in[9];
    const float* W2   = (const float*)d_in[10];
    const float* b2   = (const float*)d_in[11];
    const float* g1   = (const float*)d_in[12];
    const float* be1  = (const float*)d_in[13];
    const float* g2   = (const float*)d_in[14];
    const float* be2  = (const float*)d_in[15];
    float* out = (float*)d_out;

    char* w = (char*)d_ws;
    bf16_t* xb     = (bf16_t*)(w + 0);          // 3,276,800
    bf16_t* Wkvb   = (bf16_t*)(w + 3276800);    // 1,048,576
    bf16_t* Wob    = (bf16_t*)(w + 4325376);    //   524,288
    bf16_t* W1b    = (bf16_t*)(w + 4849664);    // 2,097,152
    bf16_t* W2b    = (bf16_t*)(w + 6946816);    // 2,097,152
    bf16_t* Kb     = (bf16_t*)(w + 9043968);    // [128][224][64]  3,670,016
    bf16_t* Vt     = (bf16_t*)(w + 12713984);   // [128][64][224]  3,670,016
    float*  G      = (float*)(w + 16384000);    // [224]
    float*  scal   = (float*)(w + 16384896);
    bf16_t* vals   = (bf16_t*)(w + 16385024);   // [3200][512] bf16
    bf16_t* hb     = (bf16_t*)(w + 19661824);   // [3200][512] bf16
    bf16_t* obuf_b = (bf16_t*)(w + 22938624);   // 2 x [3200][512] bf16 partials
    bf16_t* tb     = (bf16_t*)(w + 29492224);   // [3200][2048] bf16
    bf16_t* fbuf_b = (bf16_t*)(w + 42599424);   // 2 x [3200][512] bf16 partials

    const int M = B_ * S_;        // 3200
    const long PS = (long)M * D_; // partial stride (elements)

    // 1) merged preamble
    prep_all<<<2048, 256, 0, stream>>>(x, Wkv, Wo, W1, W2, xb, (float4*)Kb,
                                       pos, Wpos, G, scal);

    // 2) kv = x @ Wkv^T + bkv -> K [bh][224][64], V^T [bh][64][224] (400 blocks)
    mfma_gemm<128, 64, 64, 32, 3><<<dim3(16, 25, 1), 256, 0, stream>>>(
        xb, Wkvb, nullptr, 0, 0, bkv, Kb, Vt, M, 2 * D_, D_, D_);

    // 3) fused attention -> vals bf16 (B,S,D)  (512 blocks)
    attn_fused<<<dim3(128, 4, 1), 256, 0, stream>>>(Kb, Vt, G, scal, vals);

    // 4) o partials (bf16) = vals @ Wo^T, split-K x2 (400 blocks)
    mfma_gemm<128, 64, 64, 32, 5><<<dim3(8, 25, 2), 256, 0, stream>>>(
        vals, Wob, obuf_b, PS, D_, nullptr, nullptr, nullptr, M, D_, D_, 256);

    // 5) h = LN(xb + o0 + o1 + bo) -> hb bf16 (vectorized)
    add_ln_v<2, false><<<(M + 3) / 4, 256, 0, stream>>>(
        xb, obuf_b, PS, bo, g1, be1, nullptr, hb, M);

    // 6) t = relu(h @ W1^T + b1) -> bf16; 128x128 tile, 32 MFMA/step (400 blocks)
    mfma_gemm<128, 128, 64, 64, 1><<<dim3(16, 25, 1), 256, 0, stream>>>(
        hb, W1b, tb, 0, FF_, b1, nullptr, nullptr, M, FF_, D_, D_);

    // 7) f partials (bf16) = t @ W2^T, split-K x2 (400 blocks)
    mfma_gemm<128, 64, 64, 32, 5><<<dim3(8, 25, 2), 256, 0, stream>>>(
        tb, W2b, fbuf_b, PS, D_, nullptr, nullptr, nullptr, M, D_, FF_, 1024);

    // 8) out = LN(hb + f0 + f1 + b2) -> f32 (vectorized)
    add_ln_v<2, true><<<(M + 3) / 4, 256, 0, stream>>>(
        hb, fbuf_b, PS, b2, g2, be2, out, nullptr, M);
}

// Round 11
// 101.414 us; speedup vs baseline: 1.1495x; 1.0261x over previous
//
#include <hip/hip_runtime.h>
#include <hip/hip_bf16.h>

#define EPSV 1e-5f
static const int B_ = 16, S_ = 200, D_ = 512, H_ = 8, FF_ = 2048, P_ = 10, HD_ = 64;
static const int SP = 224;  // padded sequence length (14 x 16)

typedef __bf16 bf16_t;
typedef __attribute__((ext_vector_type(8))) __bf16 bf16x8;
typedef __attribute__((ext_vector_type(4))) __bf16 bf16x4;
typedef __attribute__((ext_vector_type(4))) float f32x4;

__device__ __forceinline__ void gload16(const void* g, void* l) {
    __builtin_amdgcn_global_load_lds(
        (const __attribute__((address_space(1))) void*)g,
        (__attribute__((address_space(3))) void*)l, 16, 0, 0);
}

// ---------------------------------------------------------------------------
// bf16 MFMA GEMM: C[M,N] = A[M,K] @ B[N,K]^T, 256 thr / 4 waves.
// Single-buffer LDS, 2-barrier K-loop (best-measured core, R7/R10 A/B).
// XOR source-swizzle: LDS phys chunk p of row r holds global chunk p^(r&7);
// readers apply the same XOR (bank-conflict-free ds_read_b128).
// Tiles: 128x64 (16 MFMA/step) or 128x128 (32 MFMA/step — ff1/ff2 config).
// EPI: 1 = +bias,relu -> bf16 ; 3 = +bias, scatter K/Vt bf16 (strides SP) ;
//      5 = split-K partial -> bf16 (no bias)
// ---------------------------------------------------------------------------
template <int BM, int BN, int WROWS, int WCOLS, int EPI>
__global__ __launch_bounds__(256) void mfma_gemm(
    const bf16_t* __restrict__ A,
    const bf16_t* __restrict__ Bw,
    bf16_t* __restrict__ Cb, long cBat, int ldc,
    const float* __restrict__ bias,
    bf16_t* __restrict__ kOut, bf16_t* __restrict__ vtOut,
    int M, int N, int K, int kcPerSplit)
{
    constexpr int MR = WROWS / 16, NR = WCOLS / 16;
    constexpr int NWC = BN / WCOLS;
    static_assert((4 / NWC) * WROWS == BM, "wave tiling must cover BM");
    static_assert(NWC * WCOLS == BN, "wave tiling must cover BN");

    __shared__ bf16_t Asm[BM * 64];
    __shared__ bf16_t Bsm[BN * 64];

    const int wv = threadIdx.x >> 6;
    const int ln = threadIdx.x & 63;
    const int split = blockIdx.z;
    const int rowBase = blockIdx.y * BM;
    const int colBase = blockIdx.x * BN;
    const int wr = (wv / NWC) * WROWS;
    const int wc = (wv % NWC) * WCOLS;

    const int lr8 = ln >> 3;               // row within 8-row group
    const int csw = ((ln & 7) ^ lr8) * 8;  // swizzled source chunk offset

    f32x4 acc[MR][NR] = {};

    const int kBeg = split * kcPerSplit;
    const int kEnd = kBeg + kcPerSplit;

    for (int k0 = kBeg; k0 < kEnd; k0 += 64) {
        #pragma unroll
        for (int i = 0; i < BM / 32; i++) {
            int row = i * 32 + wv * 8 + lr8;
            int gr = rowBase + row; gr = (gr < M) ? gr : (M - 1);
            gload16(A + (long)gr * K + k0 + csw, &Asm[(i * 32 + wv * 8) * 64]);
        }
        #pragma unroll
        for (int i = 0; i < BN / 32; i++) {
            int col = i * 32 + wv * 8 + lr8;
            int gc = colBase + col; gc = (gc < N) ? gc : (N - 1);
            gload16(Bw + (long)gc * K + k0 + csw, &Bsm[(i * 32 + wv * 8) * 64]);
        }
        __syncthreads();  // drains vmcnt -> LDS valid

        #pragma unroll
        for (int kk = 0; kk < 2; kk++) {
            bf16x8 af[MR], bfr[NR];
            #pragma unroll
            for (int m = 0; m < MR; m++) {
                int r = wr + m * 16 + (ln & 15);
                int pc = (kk * 4 + (ln >> 4)) ^ (r & 7);
                af[m] = *reinterpret_cast<const bf16x8*>(&Asm[r * 64 + pc * 8]);
            }
            #pragma unroll
            for (int n = 0; n < NR; n++) {
                int r = wc + n * 16 + (ln & 15);
                int pc = (kk * 4 + (ln >> 4)) ^ (r & 7);
                bfr[n] = *reinterpret_cast<const bf16x8*>(&Bsm[r * 64 + pc * 8]);
            }
            #pragma unroll
            for (int m = 0; m < MR; m++)
                #pragma unroll
                for (int n = 0; n < NR; n++)
                    acc[m][n] = __builtin_amdgcn_mfma_f32_16x16x32_bf16(
                        af[m], bfr[n], acc[m][n], 0, 0, 0);
        }
        __syncthreads();
    }

    #pragma unroll
    for (int m = 0; m < MR; m++) {
        #pragma unroll
        for (int n = 0; n < NR; n++) {
            #pragma unroll
            for (int r = 0; r < 4; r++) {
                int row = rowBase + wr + m * 16 + (ln >> 4) * 4 + r;
                int col = colBase + wc + n * 16 + (ln & 15);
                if (row >= M || col >= N) continue;
                float v = acc[m][n][r];
                if constexpr (EPI == 3) {
                    v += bias[col];
                    int b = row / S_, s = row - b * S_;
                    int h = col >> 7, w = col & 127;
                    if (w < HD_)
                        kOut[((long)(b * H_ + h) * SP + s) * HD_ + w] = (bf16_t)v;
                    else
                        vtOut[((long)(b * H_ + h) * HD_ + (w - HD_)) * SP + s] = (bf16_t)v;
                } else if constexpr (EPI == 1) {
                    v += bias[col];
                    v = fmaxf(v, 0.f);
                    Cb[(long)row * ldc + col] = (bf16_t)v;
                } else {  // 5: bf16 split-K partial
                    Cb[(long)split * cBat + (long)row * ldc + col] = (bf16_t)v;
                }
            }
        }
    }
}

// ---------------------------------------------------------------------------
// Fused attention: scores = (Krows @ Kall^T)*scale + G[col]; softmax; @ V.
// Grid: (128 bh, 4 row-tiles). 4 waves x 16 rows. No __syncthreads needed.
// ---------------------------------------------------------------------------
__global__ __launch_bounds__(256) void attn_fused(
    const bf16_t* __restrict__ Kb, const bf16_t* __restrict__ Vt,
    const float* __restrict__ G, const float* __restrict__ scalePtr,
    bf16_t* __restrict__ vals)
{
    __shared__ __align__(16) bf16_t Pl[4][16][232];

    const int bh = blockIdx.x;
    const int tile = blockIdx.y;
    const int wv = threadIdx.x >> 6;
    const int ln = threadIdx.x & 63;
    const int b = bh >> 3, h = bh & 7;
    const int rowBase = tile * 64 + wv * 16;

    const bf16_t* Kbh = Kb + (long)bh * SP * HD_;
    const bf16_t* Vbh = Vt + (long)bh * HD_ * SP;
    const float scale = scalePtr[0];

    const int lr = ln & 15;
    const int lk = (ln >> 4) * 8;

    // ---- phase 1: scores (14 col-frags, K = 64)
    f32x4 acc[14];
    #pragma unroll
    for (int n = 0; n < 14; n++) acc[n] = (f32x4){0.f, 0.f, 0.f, 0.f};

    int arow = rowBase + lr; arow = (arow < S_) ? arow : (S_ - 1);
    const bf16x8 a0 = *reinterpret_cast<const bf16x8*>(Kbh + (long)arow * HD_ + lk);
    const bf16x8 a1 = *reinterpret_cast<const bf16x8*>(Kbh + (long)arow * HD_ + 32 + lk);

    #pragma unroll
    for (int n = 0; n < 14; n++) {
        const bf16_t* bp = Kbh + (long)(n * 16 + lr) * HD_;
        bf16x8 b0 = *reinterpret_cast<const bf16x8*>(bp + lk);
        bf16x8 b1 = *reinterpret_cast<const bf16x8*>(bp + 32 + lk);
        acc[n] = __builtin_amdgcn_mfma_f32_16x16x32_bf16(a0, b0, acc[n], 0, 0, 0);
        acc[n] = __builtin_amdgcn_mfma_f32_16x16x32_bf16(a1, b1, acc[n], 0, 0, 0);
    }

    // ---- phase 2: softmax over 224 cols (4 rows/lane, 16-lane groups)
    float Gc[14];
    #pragma unroll
    for (int n = 0; n < 14; n++) Gc[n] = G[n * 16 + lr];

    #pragma unroll
    for (int r = 0; r < 4; r++) {
        float m = -1e30f;
        #pragma unroll
        for (int n = 0; n < 14; n++) {
            float v = acc[n][r] * scale + Gc[n];
            acc[n][r] = v;
            m = fmaxf(m, v);
        }
        #pragma unroll
        for (int off = 1; off < 16; off <<= 1) m = fmaxf(m, __shfl_xor(m, off));
        float s = 0.f;
        #pragma unroll
        for (int n = 0; n < 14; n++) {
            float e = __expf(acc[n][r] - m);
            acc[n][r] = e;
            s += e;
        }
        #pragma unroll
        for (int off = 1; off < 16; off <<= 1) s += __shfl_xor(s, off);
        float inv = 1.f / s;
        #pragma unroll
        for (int n = 0; n < 14; n++) acc[n][r] *= inv;
    }

    // ---- phase 3: P -> LDS (per-wave private)
    #pragma unroll
    for (int n = 0; n < 14; n++)
        #pragma unroll
        for (int r = 0; r < 4; r++)
            Pl[wv][(ln >> 4) * 4 + r][n * 16 + lr] = (bf16_t)acc[n][r];

    // ---- phase 4: PV (out 16 x 64, K = 224 = 7 x 32)
    f32x4 vacc[4] = {};
    #pragma unroll
    for (int kk = 0; kk < 7; kk++) {
        bf16x8 pa = *reinterpret_cast<const bf16x8*>(&Pl[wv][lr][kk * 32 + lk]);
        #pragma unroll
        for (int n = 0; n < 4; n++) {
            bf16x8 vb = *reinterpret_cast<const bf16x8*>(
                Vbh + (long)(n * 16 + lr) * SP + kk * 32 + lk);
            vacc[n] = __builtin_amdgcn_mfma_f32_16x16x32_bf16(pa, vb, vacc[n], 0, 0, 0);
        }
    }

    // ---- phase 5: write vals (B,S,D) bf16
    #pragma unroll
    for (int n = 0; n < 4; n++) {
        #pragma unroll
        for (int r = 0; r < 4; r++) {
            int row = rowBase + (ln >> 4) * 4 + r;
            if (row < S_)
                vals[((long)b * S_ + row) * D_ + h * HD_ + n * 16 + lr] =
                    (bf16_t)vacc[n][r];
        }
    }
}

// ---------------------------------------------------------------------------
// Merged preamble: f32->bf16 converts, targeted K/Vt pad zeroing, G + scale.
// Pads: Kb rows [200,224) per bh (contiguous 1536 elems), Vt cols [200,224)
// per (bh, d-row) (3 x bf16x8, 16B-aligned: 448d+400 ≡ 0 mod 16).
// ---------------------------------------------------------------------------
__global__ __launch_bounds__(256) void prep_all(
    const float* __restrict__ x, const float* __restrict__ Wkv,
    const float* __restrict__ Wo, const float* __restrict__ W1,
    const float* __restrict__ W2, bf16_t* __restrict__ dst,
    bf16_t* __restrict__ Kb, bf16_t* __restrict__ Vt,
    const float* __restrict__ pos, const float* __restrict__ Wpos,
    float* __restrict__ G, float* __restrict__ scal)
{
    const int gid = blockIdx.x * blockDim.x + threadIdx.x;
    const int nthr = gridDim.x * blockDim.x;
    const bf16x8 z8 = {};

    // converts: 1,130,496 float4-groups
    for (int i = gid; i < 1130496; i += nthr) {
        long e = (long)i * 4;
        const float* s; long off;
        if (e < 1638400)      { s = x;   off = e; }
        else if (e < 2162688) { s = Wkv; off = e - 1638400; }
        else if (e < 2424832) { s = Wo;  off = e - 2162688; }
        else if (e < 3473408) { s = W1;  off = e - 2424832; }
        else                  { s = W2;  off = e - 3473408; }
        float4 v = *reinterpret_cast<const float4*>(s + off);
        bf16x4 o = {(bf16_t)v.x, (bf16_t)v.y, (bf16_t)v.z, (bf16_t)v.w};
        *reinterpret_cast<bf16x4*>(dst + e) = o;
    }
    // K pad rows: 128 bh x 192 groups of 8 (rows 200..223, 64 wide)
    for (int i = gid; i < 128 * 192; i += nthr) {
        int bh = i / 192, g = i % 192;
        *reinterpret_cast<bf16x8*>(Kb + (long)bh * (SP * HD_) + 200 * 64 + g * 8) = z8;
    }
    // Vt pad cols: 128 bh x 64 rows x 3 groups of 8 (cols 200..223)
    for (int i = gid; i < 128 * 192; i += nthr) {
        int bh = i / 192, rem = i % 192, d = rem / 3, j = rem % 3;
        *reinterpret_cast<bf16x8*>(Vt + (long)bh * (HD_ * SP) + d * SP + 200 + j * 8) = z8;
    }
    // G + scale
    if (gid < SP) {
        float g = -1e30f;
        if (gid < S_) {
            g = 0.f;
            #pragma unroll
            for (int p = 6; p < 10; p++) g += pos[(long)gid * P_ + p] * Wpos[p];
        }
        G[gid] = g;
    }
    if (gid == 0) {
        float sw = 0.f;
        for (int p = 0; p < P_; p++) sw += Wpos[p];
        scal[0] = sw * 0.125f;
    }
}

// ---------------------------------------------------------------------------
// Vectorized add+LN: out = LayerNorm(a + sum_p parts[p] + bias).
// One wave per 512-col row; lane owns 8 contiguous cols (bf16x8/float4 loads).
// ---------------------------------------------------------------------------
template <int NPART, bool F32OUT>
__global__ __launch_bounds__(256) void add_ln_v(
    const bf16_t* __restrict__ a, const bf16_t* __restrict__ parts, long partStride,
    const float* __restrict__ bias,
    const float* __restrict__ g, const float* __restrict__ beta,
    float* __restrict__ outf, bf16_t* __restrict__ outb, int rows)
{
    int row = blockIdx.x * 4 + (threadIdx.x >> 6);
    int lane = threadIdx.x & 63;
    if (row >= rows) return;
    const int col = lane * 8;
    const long base = (long)row * D_ + col;

    bf16x8 a8 = *reinterpret_cast<const bf16x8*>(a + base);
    float4 b0 = *reinterpret_cast<const float4*>(bias + col);
    float4 b1 = *reinterpret_cast<const float4*>(bias + col + 4);
    const float bb[8] = {b0.x, b0.y, b0.z, b0.w, b1.x, b1.y, b1.z, b1.w};

    bf16x8 p8[NPART];
    #pragma unroll
    for (int p = 0; p < NPART; p++)
        p8[p] = *reinterpret_cast<const bf16x8*>(parts + (long)p * partStride + base);

    float v[8];
    float sum = 0.f;
    #pragma unroll
    for (int i = 0; i < 8; i++) {
        float t = (float)a8[i] + bb[i];
        #pragma unroll
        for (int p = 0; p < NPART; p++) t += (float)p8[p][i];
        v[i] = t;
        sum += t;
    }
    #pragma unroll
    for (int off = 32; off; off >>= 1) sum += __shfl_xor(sum, off);
    float mean = sum * (1.f / 512.f);
    float var = 0.f;
    #pragma unroll
    for (int i = 0; i < 8; i++) { float d = v[i] - mean; var += d * d; }
    #pragma unroll
    for (int off = 32; off; off >>= 1) var += __shfl_xor(var, off);
    float rstd = rsqrtf(var * (1.f / 512.f) + EPSV);

    float4 g0 = *reinterpret_cast<const float4*>(g + col);
    float4 g1v = *reinterpret_cast<const float4*>(g + col + 4);
    float4 e0 = *reinterpret_cast<const float4*>(beta + col);
    float4 e1 = *reinterpret_cast<const float4*>(beta + col + 4);
    const float gg[8] = {g0.x, g0.y, g0.z, g0.w, g1v.x, g1v.y, g1v.z, g1v.w};
    const float ee[8] = {e0.x, e0.y, e0.z, e0.w, e1.x, e1.y, e1.z, e1.w};

    if constexpr (F32OUT) {
        float4 o0, o1;
        o0.x = (v[0]-mean)*rstd*gg[0]+ee[0]; o0.y = (v[1]-mean)*rstd*gg[1]+ee[1];
        o0.z = (v[2]-mean)*rstd*gg[2]+ee[2]; o0.w = (v[3]-mean)*rstd*gg[3]+ee[3];
        o1.x = (v[4]-mean)*rstd*gg[4]+ee[4]; o1.y = (v[5]-mean)*rstd*gg[5]+ee[5];
        o1.z = (v[6]-mean)*rstd*gg[6]+ee[6]; o1.w = (v[7]-mean)*rstd*gg[7]+ee[7];
        *reinterpret_cast<float4*>(outf + base) = o0;
        *reinterpret_cast<float4*>(outf + base + 4) = o1;
    } else {
        bf16x8 o8;
        #pragma unroll
        for (int i = 0; i < 8; i++)
            o8[i] = (bf16_t)((v[i] - mean) * rstd * gg[i] + ee[i]);
        *reinterpret_cast<bf16x8*>(outb + base) = o8;
    }
}

extern "C" void kernel_launch(void* const* d_in, const int* in_sizes, int n_in,
                              void* d_out, int out_size, void* d_ws, size_t ws_size,
                              hipStream_t stream)
{
    const float* x    = (const float*)d_in[0];
    const float* pos  = (const float*)d_in[1];
    const float* Wkv  = (const float*)d_in[2];
    const float* bkv  = (const float*)d_in[3];
    const float* Wo   = (const float*)d_in[4];
    const float* bo   = (const float*)d_in[5];
    const float* Wpos = (const float*)d_in[6];
    const float* W1   = (const float*)d_in[8];
    const float* b1   = (const float*)d_in[9];
    const float* W2   = (const float*)d_in[10];
    const float* b2   = (const float*)d_in[11];
    const float* g1   = (const float*)d_in[12];
    const float* be1  = (const float*)d_in[13];
    const float* g2   = (const float*)d_in[14];
    const float* be2  = (const float*)d_in[15];
    float* out = (float*)d_out;

    char* w = (char*)d_ws;
    bf16_t* xb     = (bf16_t*)(w + 0);          // 3,276,800
    bf16_t* Wkvb   = (bf16_t*)(w + 3276800);    // 1,048,576
    bf16_t* Wob    = (bf16_t*)(w + 4325376);    //   524,288
    bf16_t* W1b    = (bf16_t*)(w + 4849664);    // 2,097,152
    bf16_t* W2b    = (bf16_t*)(w + 6946816);    // 2,097,152
    bf16_t* Kb     = (bf16_t*)(w + 9043968);    // [128][224][64]  3,670,016
    bf16_t* Vt     = (bf16_t*)(w + 12713984);   // [128][64][224]  3,670,016
    float*  G      = (float*)(w + 16384000);    // [224]
    float*  scal   = (float*)(w + 16384896);
    bf16_t* vals   = (bf16_t*)(w + 16385024);   // [3200][512] bf16
    bf16_t* hb     = (bf16_t*)(w + 19661824);   // [3200][512] bf16
    bf16_t* obuf_b = (bf16_t*)(w + 22938624);   // 2 x [3200][512] bf16 partials
    bf16_t* tb     = (bf16_t*)(w + 29492224);   // [3200][2048] bf16
    bf16_t* fbuf_b = (bf16_t*)(w + 42599424);   // 4 x [3200][512] bf16 partials

    const int M = B_ * S_;        // 3200
    const long PS = (long)M * D_; // partial stride (elements)

    // 1) merged preamble
    prep_all<<<2048, 256, 0, stream>>>(x, Wkv, Wo, W1, W2, xb, Kb, Vt,
                                       pos, Wpos, G, scal);

    // 2) kv = x @ Wkv^T + bkv -> K [bh][224][64], V^T [bh][64][224] (400 blocks)
    mfma_gemm<128, 64, 64, 32, 3><<<dim3(16, 25, 1), 256, 0, stream>>>(
        xb, Wkvb, nullptr, 0, 0, bkv, Kb, Vt, M, 2 * D_, D_, D_);

    // 3) fused attention -> vals bf16 (B,S,D)  (512 blocks)
    attn_fused<<<dim3(128, 4, 1), 256, 0, stream>>>(Kb, Vt, G, scal, vals);

    // 4) o partials (bf16) = vals @ Wo^T, split-K x2 (400 blocks)
    mfma_gemm<128, 64, 64, 32, 5><<<dim3(8, 25, 2), 256, 0, stream>>>(
        vals, Wob, obuf_b, PS, D_, nullptr, nullptr, nullptr, M, D_, D_, 256);

    // 5) h = LN(xb + o0 + o1 + bo) -> hb bf16 (vectorized)
    add_ln_v<2, false><<<(M + 3) / 4, 256, 0, stream>>>(
        xb, obuf_b, PS, bo, g1, be1, nullptr, hb, M);

    // 6) t = relu(h @ W1^T + b1) -> bf16; 128x128 tile, 32 MFMA/step (400 blocks)
    mfma_gemm<128, 128, 64, 64, 1><<<dim3(16, 25, 1), 256, 0, stream>>>(
        hb, W1b, tb, 0, FF_, b1, nullptr, nullptr, M, FF_, D_, D_);

    // 7) f partials (bf16) = t @ W2^T; 128x128 tile, split-K x4 (400 blocks)
    mfma_gemm<128, 128, 64, 64, 5><<<dim3(4, 25, 4), 256, 0, stream>>>(
        tb, W2b, fbuf_b, PS, D_, nullptr, nullptr, nullptr, M, D_, FF_, 512);

    // 8) out = LN(hb + f0..f3 + b2) -> f32 (vectorized)
    add_ln_v<4, true><<<(M + 3) / 4, 256, 0, stream>>>(
        hb, fbuf_b, PS, b2, g2, be2, out, nullptr, M);
}